// Round 7
// baseline (192.656 us; speedup 1.0000x reference)
//
#include <hip/hip_runtime.h>

constexpr int NUM_GRAPHS = 64;

typedef __attribute__((ext_vector_type(8))) short bf16x8;
typedef __attribute__((ext_vector_type(4))) float f32x4;

__device__ inline unsigned short f2bf(float f) {
    unsigned u = __float_as_uint(f);
    unsigned r = (u + 0x7FFFu + ((u >> 16) & 1u)) >> 16;
    return (unsigned short)r;
}
// packed pair: bits[15:0]=bf16(lo), bits[31:16]=bf16(hi) — single HW instruction
__device__ inline unsigned cvt_pk_bf16(float lo, float hi) {
    unsigned r;
    asm("v_cvt_pk_bf16_f32 %0, %1, %2" : "=v"(r) : "v"(lo), "v"(hi));
    return r;
}
__device__ inline float bflo(unsigned v) { return __uint_as_float(v << 16); }
__device__ inline float bfhi(unsigned v) { return __uint_as_float(v & 0xFFFF0000u); }

// ---------------- prep: zero cnt + zero scan state/ticket + wcast W1,W2 + graph bounds ----------------

__global__ void prep_k(int* __restrict__ cnt, int n,
                       const float* __restrict__ W1, const float* __restrict__ W2,
                       unsigned short* __restrict__ Wt1, unsigned short* __restrict__ Wt2,
                       int* __restrict__ state_i, int* __restrict__ ticket,
                       const int* __restrict__ batch, int* __restrict__ gstart) {
    int idx = blockIdx.x * 256 + threadIdx.x;
    if (idx < n) {
        cnt[idx] = 0;
    } else if (idx < n + 16384) {
        int j = idx - n;
        int k = j & 127, c = j >> 7;
        Wt1[c * 128 + k] = f2bf(W1[k * 128 + c]);
    } else if (idx < n + 24576) {
        int j = idx - n - 16384;
        int k = j & 127, c = j >> 7;
        Wt2[c * 128 + k] = f2bf(W2[k * 64 + c]);
    } else if (idx < n + 24576 + 512) {
        state_i[idx - n - 24576] = 0;
    } else if (idx == n + 24576 + 512) {
        *ticket = 0;
    } else if (idx <= n + 24576 + 513 + NUM_GRAPHS) {
        int g = idx - (n + 24576 + 513);
        int lo = 0, hi = n;
        while (lo < hi) {
            int mid = (lo + hi) >> 1;
            if (batch[mid] < g) lo = mid + 1; else hi = mid;
        }
        gstart[g] = lo;
    }
}

// ---------------- CSR build ----------------

__global__ void count_edges_k(const int* __restrict__ dst, int E, int* __restrict__ cnt) {
    int e = blockIdx.x * 256 + threadIdx.x;
    if (e < E) atomicAdd(&cnt[dst[e]], 1);
}

// single-pass decoupled-lookback exclusive scan; also emits cursor + dinv
__global__ __launch_bounds__(256) void scan_onepass_k(const int* __restrict__ cnt, int n,
                                                      int* __restrict__ rowptr, int* __restrict__ cursor,
                                                      float* __restrict__ dinv,
                                                      unsigned long long* __restrict__ state,
                                                      int* __restrict__ ticket) {
    __shared__ int s[256];
    __shared__ int sbid, sex;
    int t = threadIdx.x;
    if (t == 0) sbid = atomicAdd(ticket, 1);
    __syncthreads();
    const int bid = sbid;
    const int i = bid * 256 + t;
    const int v = (i < n) ? cnt[i] : 0;
    s[t] = v;
    __syncthreads();
    for (int off = 1; off < 256; off <<= 1) {
        int u = (t >= off) ? s[t - off] : 0;
        __syncthreads();
        s[t] += u;
        __syncthreads();
    }
    const int incl = s[t];
    const int total = s[255];
    if (t == 0) {
        int ex = 0;
        if (bid == 0) {
            __hip_atomic_store(&state[0], (2ull << 32) | (unsigned)total,
                               __ATOMIC_RELEASE, __HIP_MEMORY_SCOPE_AGENT);
        } else {
            __hip_atomic_store(&state[bid], (1ull << 32) | (unsigned)total,
                               __ATOMIC_RELEASE, __HIP_MEMORY_SCOPE_AGENT);
            int j = bid - 1;
            while (true) {
                unsigned long long st = __hip_atomic_load(&state[j], __ATOMIC_ACQUIRE,
                                                          __HIP_MEMORY_SCOPE_AGENT);
                unsigned f = (unsigned)(st >> 32);
                if (f == 0) continue;           // not yet published — spin
                ex += (int)(unsigned)st;
                if (f == 2) break;              // inclusive prefix — done
                --j;                            // aggregate — keep walking
            }
            __hip_atomic_store(&state[bid], (2ull << 32) | (unsigned)(ex + total),
                               __ATOMIC_RELEASE, __HIP_MEMORY_SCOPE_AGENT);
        }
        sex = ex;
    }
    __syncthreads();
    const int excl = sex + incl - v;
    if (i < n) {
        rowptr[i] = excl;
        cursor[i] = excl;
        dinv[i] = rsqrtf((float)(v + 1));  // +1 self-loop
    }
    if (i == n - 1) rowptr[n] = excl + v;
}

__global__ void fill_csr_k(const int* __restrict__ src, const int* __restrict__ dst, int E,
                           int* __restrict__ cursor, int* __restrict__ csr_src) {
    int e = blockIdx.x * 256 + threadIdx.x;
    if (e < E) {
        int d = dst[e];
        int pos = atomicAdd(&cursor[d], 1);
        csr_src[pos] = src[e];
    }
}

// ---------------- MFMA GEMM: Pc[chunk][M][32] = bf16(dinv[row] * (A[M,128] @ W[128,N])) ----------------

template <int N, bool ACHUNKED>
__global__ __launch_bounds__(256) void mfma_gemm_k(const void* __restrict__ Av, const unsigned short* __restrict__ Wt,
                                                   const float* __restrict__ dinv, unsigned short* __restrict__ Pc, int M) {
    constexpr int NF = N / 16;
    constexpr int LDSK = 136;
    __shared__ unsigned short Ws[N * LDSK];
    const int tid = threadIdx.x;

    for (int idx = tid; idx < N * 32; idx += 256) {
        int nn = idx >> 5, c = idx & 31;
        *(ushort4*)(&Ws[nn * LDSK + c * 4]) = *(const ushort4*)(Wt + nn * 128 + c * 4);
    }
    __syncthreads();

    const int lane = tid & 63;
    const int wrow = blockIdx.x * 64 + (tid >> 6) * 16 + (lane & 15);
    const int k8 = (lane >> 4) * 8;
    const int arow = (wrow < M) ? wrow : (M - 1);

    f32x4 acc[NF] = {};
    const float* Af = (const float*)Av;
    const unsigned short* Ab = (const unsigned short*)Av;

#pragma unroll
    for (int ko = 0; ko < 4; ++ko) {
        bf16x8 a;
        if (ACHUNKED) {
            a = *(const bf16x8*)(Ab + ((size_t)ko * M + arow) * 32 + k8);
        } else {
            const int kq = ko * 32 + k8;
            float4 lo = *(const float4*)(Af + (size_t)arow * 128 + kq);
            float4 hi = *(const float4*)(Af + (size_t)arow * 128 + kq + 4);
            unsigned au[4];
            au[0] = cvt_pk_bf16(lo.x, lo.y);
            au[1] = cvt_pk_bf16(lo.z, lo.w);
            au[2] = cvt_pk_bf16(hi.x, hi.y);
            au[3] = cvt_pk_bf16(hi.z, hi.w);
            a = *(const bf16x8*)au;
        }
        const int k0 = ko * 32 + k8;
#pragma unroll
        for (int nf = 0; nf < NF; ++nf) {
            bf16x8 b = *(const bf16x8*)(&Ws[(nf * 16 + (lane & 15)) * LDSK + k0]);
            acc[nf] = __builtin_amdgcn_mfma_f32_16x16x32_bf16(a, b, acc[nf], 0, 0, 0);
        }
    }

    const int crow0 = blockIdx.x * 64 + (tid >> 6) * 16 + (lane >> 4) * 4;
    const int ccol = lane & 15;
#pragma unroll
    for (int r = 0; r < 4; ++r) {
        int row = crow0 + r;
        if (row < M) {
            float sc = dinv[row];
#pragma unroll
            for (int j = 0; j < NF / 2; ++j) {
                unsigned pr = cvt_pk_bf16(acc[2 * j][r] * sc, acc[2 * j + 1][r] * sc);
                unsigned short* base = Pc + ((size_t)j * M + row) * 32 + ccol;
                base[0] = (unsigned short)(pr & 0xFFFFu);
                base[16] = (unsigned short)(pr >> 16);
            }
        }
    }
}

// ---------------- Chunked aggregation with batched-ILP gather ----------------

template <int CHUNKS, bool RELU>
__global__ __launch_bounds__(256) void aggc_k(const unsigned short* __restrict__ pc, const float* __restrict__ dinv,
                                              const int* __restrict__ rowptr, const int* __restrict__ csr_src,
                                              const float* __restrict__ bias, unsigned short* __restrict__ outc, int n) {
    constexpr int SUB = 8 / CHUNKS;
    const int b = blockIdx.x;
    const int chunk = (b & 7) / SUB;
    const int part = (b >> 3) * SUB + (b & (SUB - 1));
    const int nid = part * 16 + (threadIdx.x >> 4);  // quarter-wave per node
    const int l = threadIdx.x & 15;
    if (nid >= n) return;

    const unsigned short* p = pc + (size_t)chunk * n * 32;
    float di = dinv[nid];
    int e0 = rowptr[nid], e1 = rowptr[nid + 1];
    unsigned v = *(const unsigned*)(p + (size_t)nid * 32 + l * 2);  // self term
    float ax = bflo(v), ay = bfhi(v);

    const int start = e0 & ~3;  // align for int4 loads; csr_src padded by 16 ints
    for (int base = start; base < e1; base += 16) {
        int idx[16];
#pragma unroll
        for (int j = 0; j < 4; ++j) {
            int4 q = *(const int4*)(csr_src + base + j * 4);
            idx[j * 4 + 0] = q.x; idx[j * 4 + 1] = q.y;
            idx[j * 4 + 2] = q.z; idx[j * 4 + 3] = q.w;
        }
        unsigned w[16];
        bool m[16];
#pragma unroll
        for (int i = 0; i < 16; ++i) {
            int ee = base + i;
            m[i] = (ee >= e0) & (ee < e1);
            int s = m[i] ? idx[i] : nid;
            w[i] = *(const unsigned*)(p + (size_t)s * 32 + l * 2);
        }
#pragma unroll
        for (int i = 0; i < 16; ++i) {
            ax += m[i] ? bflo(w[i]) : 0.f;
            ay += m[i] ? bfhi(w[i]) : 0.f;
        }
    }

    int c0 = chunk * 32 + l * 2;
    ax = di * ax + bias[c0 + 0];
    ay = di * ay + bias[c0 + 1];
    if (RELU) { ax = fmaxf(ax, 0.f); ay = fmaxf(ay, 0.f); }
    *(unsigned*)(outc + ((size_t)chunk * n + nid) * 32 + l * 2) = cvt_pk_bf16(ax, ay);
}

// ---------------- Pooling (h chunked [2][n][32]); 512 threads, 4-wide ILP ----------------

__global__ __launch_bounds__(512) void pool2_k(const unsigned short* __restrict__ h, const int* __restrict__ gstart,
                                               float* __restrict__ out, int n) {
    int g = blockIdx.x;
    int s = gstart[g], e = gstart[g + 1];
    int rg = threadIdx.x >> 5;   // 16 row-groups
    int l = threadIdx.x & 31;
    const unsigned short* hc = h + (size_t)(l >> 4) * n * 32;
    const int c2 = (l & 15) * 2;
    float ax = 0.f, ay = 0.f;
    int i = s + rg;
    for (; i + 48 < e; i += 64) {
        unsigned v0 = *(const unsigned*)(hc + (size_t)i * 32 + c2);
        unsigned v1 = *(const unsigned*)(hc + (size_t)(i + 16) * 32 + c2);
        unsigned v2 = *(const unsigned*)(hc + (size_t)(i + 32) * 32 + c2);
        unsigned v3 = *(const unsigned*)(hc + (size_t)(i + 48) * 32 + c2);
        ax += bflo(v0) + bflo(v1) + bflo(v2) + bflo(v3);
        ay += bfhi(v0) + bfhi(v1) + bfhi(v2) + bfhi(v3);
    }
    for (; i < e; i += 16) {
        unsigned v = *(const unsigned*)(hc + (size_t)i * 32 + c2);
        ax += bflo(v);
        ay += bfhi(v);
    }
    __shared__ float red[16][64];
    int col = (l >> 4) * 32 + c2;
    red[rg][col + 0] = ax;
    red[rg][col + 1] = ay;
    __syncthreads();
    if (threadIdx.x < 64) {
        int c = threadIdx.x;
        float vv = 0.f;
#pragma unroll
        for (int r = 0; r < 16; ++r) vv += red[r][c];
        int cc = e - s;
        out[g * 64 + c] = vv / (float)(cc > 1 ? cc : 1);
    }
}

// ---------------- launch ----------------

extern "C" void kernel_launch(void* const* d_in, const int* in_sizes, int n_in,
                              void* d_out, int out_size, void* d_ws, size_t ws_size,
                              hipStream_t stream) {
    const float* x = (const float*)d_in[0];
    const int* edge = (const int*)d_in[1];
    const int* batch = (const int*)d_in[2];
    const float* W1 = (const float*)d_in[3];
    const float* b1 = (const float*)d_in[4];
    const float* W2 = (const float*)d_in[5];
    const float* b2 = (const float*)d_in[6];

    const int n = in_sizes[0] / 128;
    const int E = in_sizes[1] / 2;
    const int* esrc = edge;
    const int* edst = edge + E;

    char* ws = (char*)d_ws;
    size_t off = 0;
    auto alloc = [&](size_t bytes) -> char* {
        char* pp = ws + off;
        off = (off + bytes + 255) & ~(size_t)255;
        return pp;
    };
    int* cnt = (int*)alloc((size_t)n * sizeof(int));
    int* rowptr = (int*)alloc((size_t)(n + 1) * sizeof(int));
    int* cursor = (int*)alloc((size_t)n * sizeof(int));
    unsigned long long* state = (unsigned long long*)alloc(256 * sizeof(unsigned long long));
    int* ticket = (int*)alloc(256);
    int* gstart = (int*)alloc((NUM_GRAPHS + 1) * sizeof(int));
    float* dinv = (float*)alloc((size_t)n * sizeof(float));
    int* csr_src = (int*)alloc(((size_t)E + 16) * sizeof(int));  // +16 pad for batch loads
    unsigned short* Wt1 = (unsigned short*)alloc(128 * 128 * sizeof(short));
    unsigned short* Wt2 = (unsigned short*)alloc(128 * 64 * sizeof(short));
    unsigned short* p1 = (unsigned short*)alloc((size_t)n * 128 * sizeof(short));   // [4][n][32]
    unsigned short* hagg = (unsigned short*)alloc((size_t)n * 128 * sizeof(short)); // [4][n][32]
    unsigned short* p2 = (unsigned short*)alloc((size_t)n * 64 * sizeof(short));    // [2][n][32]
    unsigned short* h2 = (unsigned short*)alloc((size_t)n * 64 * sizeof(short));    // [2][n][32]
    (void)ws_size;

    const int eb = (E + 255) / 256;
    const int nb = (n + 255) / 256;  // scan tiles (n=50000 -> 196, fits state[256])

    const int prep_items = n + 24576 + 513 + NUM_GRAPHS + 1;
    prep_k<<<(prep_items + 255) / 256, 256, 0, stream>>>(cnt, n, W1, W2, Wt1, Wt2,
                                                         (int*)state, ticket, batch, gstart);
    count_edges_k<<<eb, 256, 0, stream>>>(edst, E, cnt);
    scan_onepass_k<<<nb, 256, 0, stream>>>(cnt, n, rowptr, cursor, dinv, state, ticket);
    fill_csr_k<<<eb, 256, 0, stream>>>(esrc, edst, E, cursor, csr_src);

    const int gb = (n + 63) / 64;
    const int parts = (n + 15) / 16;
    const int grid4 = 8 * ((parts + 1) / 2);
    const int grid2 = 8 * ((parts + 3) / 4);

    // conv1
    mfma_gemm_k<128, false><<<gb, 256, 0, stream>>>(x, Wt1, dinv, p1, n);
    aggc_k<4, true><<<grid4, 256, 0, stream>>>(p1, dinv, rowptr, csr_src, b1, hagg, n);

    // conv2
    mfma_gemm_k<64, true><<<gb, 256, 0, stream>>>(hagg, Wt2, dinv, p2, n);
    aggc_k<2, false><<<grid2, 256, 0, stream>>>(p2, dinv, rowptr, csr_src, b2, h2, n);

    // mean pool
    pool2_k<<<NUM_GRAPHS, 512, 0, stream>>>(h2, gstart, (float*)d_out, n);
}

// Round 8
// 153.507 us; speedup vs baseline: 1.2550x; 1.2550x over previous
//
#include <hip/hip_runtime.h>

constexpr int NUM_GRAPHS = 64;

typedef __attribute__((ext_vector_type(8))) short bf16x8;
typedef __attribute__((ext_vector_type(4))) float f32x4;

__device__ inline unsigned short f2bf(float f) {
    unsigned u = __float_as_uint(f);
    unsigned r = (u + 0x7FFFu + ((u >> 16) & 1u)) >> 16;
    return (unsigned short)r;
}
// packed pair: bits[15:0]=bf16(lo), bits[31:16]=bf16(hi) — single HW instruction
__device__ inline unsigned cvt_pk_bf16(float lo, float hi) {
    unsigned r;
    asm("v_cvt_pk_bf16_f32 %0, %1, %2" : "=v"(r) : "v"(lo), "v"(hi));
    return r;
}
__device__ inline float bflo(unsigned v) { return __uint_as_float(v << 16); }
__device__ inline float bfhi(unsigned v) { return __uint_as_float(v & 0xFFFF0000u); }

// ---------------- prep: zero cnt + wcast W1,W2 + graph bounds ----------------

__global__ void prep_k(int* __restrict__ cnt, int n,
                       const float* __restrict__ W1, const float* __restrict__ W2,
                       unsigned short* __restrict__ Wt1, unsigned short* __restrict__ Wt2,
                       const int* __restrict__ batch, int* __restrict__ gstart) {
    int idx = blockIdx.x * 256 + threadIdx.x;
    if (idx < n) {
        cnt[idx] = 0;
    } else if (idx < n + 16384) {
        int j = idx - n;
        int k = j & 127, c = j >> 7;
        Wt1[c * 128 + k] = f2bf(W1[k * 128 + c]);
    } else if (idx < n + 24576) {
        int j = idx - n - 16384;
        int k = j & 127, c = j >> 7;
        Wt2[c * 128 + k] = f2bf(W2[k * 64 + c]);
    } else if (idx <= n + 24576 + NUM_GRAPHS) {
        int g = idx - (n + 24576);
        int lo = 0, hi = n;
        while (lo < hi) {
            int mid = (lo + hi) >> 1;
            if (batch[mid] < g) lo = mid + 1; else hi = mid;
        }
        gstart[g] = lo;
    }
}

// ---------------- CSR build ----------------

__global__ void count_edges_k(const int* __restrict__ dst, int E, int* __restrict__ cnt) {
    int e = blockIdx.x * 256 + threadIdx.x;
    if (e < E) atomicAdd(&cnt[dst[e]], 1);
}

__global__ void scan_part_k(const int* __restrict__ cnt, int n, int* __restrict__ bsum) {
    __shared__ int s[256];
    int t = threadIdx.x;
    int i = blockIdx.x * 256 + t;
    s[t] = (i < n) ? cnt[i] : 0;
    __syncthreads();
    for (int off = 128; off > 0; off >>= 1) {
        if (t < off) s[t] += s[t + off];
        __syncthreads();
    }
    if (t == 0) bsum[blockIdx.x] = s[0];
}

// single block, nb <= 256: exclusive scan of block sums
__global__ void scan_top_k(int* __restrict__ bsum, int nb) {
    __shared__ int s[256];
    int t = threadIdx.x;
    s[t] = (t < nb) ? bsum[t] : 0;
    __syncthreads();
    for (int off = 1; off < 256; off <<= 1) {
        int v = (t >= off) ? s[t - off] : 0;
        __syncthreads();
        s[t] += v;
        __syncthreads();
    }
    int ex = (t == 0) ? 0 : s[t - 1];
    if (t < nb) bsum[t] = ex;
}

// also computes dinv (fused)
__global__ void scan_final_k(const int* __restrict__ cnt, int n, const int* __restrict__ boff,
                             int* __restrict__ rowptr, int* __restrict__ cursor,
                             float* __restrict__ dinv) {
    __shared__ int s[256];
    int t = threadIdx.x;
    int i = blockIdx.x * 256 + t;
    int v = (i < n) ? cnt[i] : 0;
    s[t] = v;
    __syncthreads();
    for (int off = 1; off < 256; off <<= 1) {
        int u = (t >= off) ? s[t - off] : 0;
        __syncthreads();
        s[t] += u;
        __syncthreads();
    }
    int incl = s[t];
    int ex = incl - v + boff[blockIdx.x];
    if (i < n) {
        rowptr[i] = ex;
        cursor[i] = ex;
        dinv[i] = rsqrtf((float)(v + 1));  // +1 self-loop
    }
    if (i == n - 1) rowptr[n] = ex + v;
}

__global__ void fill_csr_k(const int* __restrict__ src, const int* __restrict__ dst, int E,
                           int* __restrict__ cursor, int* __restrict__ csr_src) {
    int e = blockIdx.x * 256 + threadIdx.x;
    if (e < E) {
        int d = dst[e];
        int pos = atomicAdd(&cursor[d], 1);
        csr_src[pos] = src[e];
    }
}

// ---------------- MFMA GEMM: Pc[chunk][M][32] = bf16(dinv[row] * (A[M,128] @ W[128,N])) ----------------

template <int N, bool ACHUNKED>
__global__ __launch_bounds__(256) void mfma_gemm_k(const void* __restrict__ Av, const unsigned short* __restrict__ Wt,
                                                   const float* __restrict__ dinv, unsigned short* __restrict__ Pc, int M) {
    constexpr int NF = N / 16;
    constexpr int LDSK = 136;
    __shared__ unsigned short Ws[N * LDSK];
    const int tid = threadIdx.x;

    for (int idx = tid; idx < N * 32; idx += 256) {
        int nn = idx >> 5, c = idx & 31;
        *(ushort4*)(&Ws[nn * LDSK + c * 4]) = *(const ushort4*)(Wt + nn * 128 + c * 4);
    }
    __syncthreads();

    const int lane = tid & 63;
    const int wrow = blockIdx.x * 64 + (tid >> 6) * 16 + (lane & 15);
    const int k8 = (lane >> 4) * 8;
    const int arow = (wrow < M) ? wrow : (M - 1);

    f32x4 acc[NF] = {};
    const float* Af = (const float*)Av;
    const unsigned short* Ab = (const unsigned short*)Av;

#pragma unroll
    for (int ko = 0; ko < 4; ++ko) {
        bf16x8 a;
        if (ACHUNKED) {
            a = *(const bf16x8*)(Ab + ((size_t)ko * M + arow) * 32 + k8);
        } else {
            const int kq = ko * 32 + k8;
            float4 lo = *(const float4*)(Af + (size_t)arow * 128 + kq);
            float4 hi = *(const float4*)(Af + (size_t)arow * 128 + kq + 4);
            unsigned au[4];
            au[0] = cvt_pk_bf16(lo.x, lo.y);
            au[1] = cvt_pk_bf16(lo.z, lo.w);
            au[2] = cvt_pk_bf16(hi.x, hi.y);
            au[3] = cvt_pk_bf16(hi.z, hi.w);
            a = *(const bf16x8*)au;
        }
        const int k0 = ko * 32 + k8;
#pragma unroll
        for (int nf = 0; nf < NF; ++nf) {
            bf16x8 b = *(const bf16x8*)(&Ws[(nf * 16 + (lane & 15)) * LDSK + k0]);
            acc[nf] = __builtin_amdgcn_mfma_f32_16x16x32_bf16(a, b, acc[nf], 0, 0, 0);
        }
    }

    const int crow0 = blockIdx.x * 64 + (tid >> 6) * 16 + (lane >> 4) * 4;
    const int ccol = lane & 15;
#pragma unroll
    for (int r = 0; r < 4; ++r) {
        int row = crow0 + r;
        if (row < M) {
            float sc = dinv[row];
#pragma unroll
            for (int j = 0; j < NF / 2; ++j) {
                unsigned pr = cvt_pk_bf16(acc[2 * j][r] * sc, acc[2 * j + 1][r] * sc);
                unsigned short* base = Pc + ((size_t)j * M + row) * 32 + ccol;
                base[0] = (unsigned short)(pr & 0xFFFFu);
                base[16] = (unsigned short)(pr >> 16);
            }
        }
    }
}

// ---------------- Chunked aggregation with batched-ILP gather ----------------

template <int CHUNKS, bool RELU>
__global__ __launch_bounds__(256) void aggc_k(const unsigned short* __restrict__ pc, const float* __restrict__ dinv,
                                              const int* __restrict__ rowptr, const int* __restrict__ csr_src,
                                              const float* __restrict__ bias, unsigned short* __restrict__ outc, int n) {
    constexpr int SUB = 8 / CHUNKS;
    const int b = blockIdx.x;
    const int chunk = (b & 7) / SUB;
    const int part = (b >> 3) * SUB + (b & (SUB - 1));
    const int nid = part * 16 + (threadIdx.x >> 4);  // quarter-wave per node
    const int l = threadIdx.x & 15;
    if (nid >= n) return;

    const unsigned short* p = pc + (size_t)chunk * n * 32;
    float di = dinv[nid];
    int e0 = rowptr[nid], e1 = rowptr[nid + 1];
    unsigned v = *(const unsigned*)(p + (size_t)nid * 32 + l * 2);  // self term
    float ax = bflo(v), ay = bfhi(v);

    const int start = e0 & ~3;  // align for int4 loads; csr_src padded by 16 ints
    for (int base = start; base < e1; base += 16) {
        int idx[16];
#pragma unroll
        for (int j = 0; j < 4; ++j) {
            int4 q = *(const int4*)(csr_src + base + j * 4);
            idx[j * 4 + 0] = q.x; idx[j * 4 + 1] = q.y;
            idx[j * 4 + 2] = q.z; idx[j * 4 + 3] = q.w;
        }
        unsigned w[16];
        bool m[16];
#pragma unroll
        for (int i = 0; i < 16; ++i) {
            int ee = base + i;
            m[i] = (ee >= e0) & (ee < e1);
            int s = m[i] ? idx[i] : nid;
            w[i] = *(const unsigned*)(p + (size_t)s * 32 + l * 2);
        }
#pragma unroll
        for (int i = 0; i < 16; ++i) {
            ax += m[i] ? bflo(w[i]) : 0.f;
            ay += m[i] ? bfhi(w[i]) : 0.f;
        }
    }

    int c0 = chunk * 32 + l * 2;
    ax = di * ax + bias[c0 + 0];
    ay = di * ay + bias[c0 + 1];
    if (RELU) { ax = fmaxf(ax, 0.f); ay = fmaxf(ay, 0.f); }
    *(unsigned*)(outc + ((size_t)chunk * n + nid) * 32 + l * 2) = cvt_pk_bf16(ax, ay);
}

// ---------------- Pooling (h chunked [2][n][32]); 512 threads, 4-wide ILP ----------------

__global__ __launch_bounds__(512) void pool2_k(const unsigned short* __restrict__ h, const int* __restrict__ gstart,
                                               float* __restrict__ out, int n) {
    int g = blockIdx.x;
    int s = gstart[g], e = gstart[g + 1];
    int rg = threadIdx.x >> 5;   // 16 row-groups
    int l = threadIdx.x & 31;
    const unsigned short* hc = h + (size_t)(l >> 4) * n * 32;
    const int c2 = (l & 15) * 2;
    float ax = 0.f, ay = 0.f;
    int i = s + rg;
    for (; i + 48 < e; i += 64) {
        unsigned v0 = *(const unsigned*)(hc + (size_t)i * 32 + c2);
        unsigned v1 = *(const unsigned*)(hc + (size_t)(i + 16) * 32 + c2);
        unsigned v2 = *(const unsigned*)(hc + (size_t)(i + 32) * 32 + c2);
        unsigned v3 = *(const unsigned*)(hc + (size_t)(i + 48) * 32 + c2);
        ax += bflo(v0) + bflo(v1) + bflo(v2) + bflo(v3);
        ay += bfhi(v0) + bfhi(v1) + bfhi(v2) + bfhi(v3);
    }
    for (; i < e; i += 16) {
        unsigned v = *(const unsigned*)(hc + (size_t)i * 32 + c2);
        ax += bflo(v);
        ay += bfhi(v);
    }
    __shared__ float red[16][64];
    int col = (l >> 4) * 32 + c2;
    red[rg][col + 0] = ax;
    red[rg][col + 1] = ay;
    __syncthreads();
    if (threadIdx.x < 64) {
        int c = threadIdx.x;
        float vv = 0.f;
#pragma unroll
        for (int r = 0; r < 16; ++r) vv += red[r][c];
        int cc = e - s;
        out[g * 64 + c] = vv / (float)(cc > 1 ? cc : 1);
    }
}

// ---------------- launch ----------------

extern "C" void kernel_launch(void* const* d_in, const int* in_sizes, int n_in,
                              void* d_out, int out_size, void* d_ws, size_t ws_size,
                              hipStream_t stream) {
    const float* x = (const float*)d_in[0];
    const int* edge = (const int*)d_in[1];
    const int* batch = (const int*)d_in[2];
    const float* W1 = (const float*)d_in[3];
    const float* b1 = (const float*)d_in[4];
    const float* W2 = (const float*)d_in[5];
    const float* b2 = (const float*)d_in[6];

    const int n = in_sizes[0] / 128;
    const int E = in_sizes[1] / 2;
    const int* esrc = edge;
    const int* edst = edge + E;

    char* ws = (char*)d_ws;
    size_t off = 0;
    auto alloc = [&](size_t bytes) -> char* {
        char* pp = ws + off;
        off = (off + bytes + 255) & ~(size_t)255;
        return pp;
    };
    int* cnt = (int*)alloc((size_t)n * sizeof(int));
    int* rowptr = (int*)alloc((size_t)(n + 1) * sizeof(int));
    int* cursor = (int*)alloc((size_t)n * sizeof(int));
    int* bsum = (int*)alloc(256 * sizeof(int));
    int* gstart = (int*)alloc((NUM_GRAPHS + 1) * sizeof(int));
    float* dinv = (float*)alloc((size_t)n * sizeof(float));
    int* csr_src = (int*)alloc(((size_t)E + 16) * sizeof(int));  // +16 pad for batch loads
    unsigned short* Wt1 = (unsigned short*)alloc(128 * 128 * sizeof(short));
    unsigned short* Wt2 = (unsigned short*)alloc(128 * 64 * sizeof(short));
    unsigned short* p1 = (unsigned short*)alloc((size_t)n * 128 * sizeof(short));   // [4][n][32]
    unsigned short* hagg = (unsigned short*)alloc((size_t)n * 128 * sizeof(short)); // [4][n][32]
    unsigned short* p2 = (unsigned short*)alloc((size_t)n * 64 * sizeof(short));    // [2][n][32]
    unsigned short* h2 = (unsigned short*)alloc((size_t)n * 64 * sizeof(short));    // [2][n][32]
    (void)ws_size;

    const int eb = (E + 255) / 256;
    const int nb = (n + 255) / 256;  // <= 256 for scan_top (n=50000 -> 196)

    const int prep_items = n + 24576 + NUM_GRAPHS + 1;
    prep_k<<<(prep_items + 255) / 256, 256, 0, stream>>>(cnt, n, W1, W2, Wt1, Wt2, batch, gstart);
    count_edges_k<<<eb, 256, 0, stream>>>(edst, E, cnt);
    scan_part_k<<<nb, 256, 0, stream>>>(cnt, n, bsum);
    scan_top_k<<<1, 256, 0, stream>>>(bsum, nb);
    scan_final_k<<<nb, 256, 0, stream>>>(cnt, n, bsum, rowptr, cursor, dinv);
    fill_csr_k<<<eb, 256, 0, stream>>>(esrc, edst, E, cursor, csr_src);

    const int gb = (n + 63) / 64;
    const int parts = (n + 15) / 16;
    const int grid4 = 8 * ((parts + 1) / 2);
    const int grid2 = 8 * ((parts + 3) / 4);

    // conv1
    mfma_gemm_k<128, false><<<gb, 256, 0, stream>>>(x, Wt1, dinv, p1, n);
    aggc_k<4, true><<<grid4, 256, 0, stream>>>(p1, dinv, rowptr, csr_src, b1, hagg, n);

    // conv2
    mfma_gemm_k<64, true><<<gb, 256, 0, stream>>>(hagg, Wt2, dinv, p2, n);
    aggc_k<2, false><<<grid2, 256, 0, stream>>>(p2, dinv, rowptr, csr_src, b2, h2, n);

    // mean pool
    pool2_k<<<NUM_GRAPHS, 512, 0, stream>>>(h2, gstart, (float*)d_out, n);
}